// Round 19
// baseline (301.038 us; speedup 1.0000x reference)
//
#include <hip/hip_runtime.h>
#include <hip/hip_bf16.h>
#include <stdint.h>

typedef unsigned short u16;
typedef __attribute__((ext_vector_type(8))) short short8;
typedef __attribute__((ext_vector_type(4))) float f32x4;

#define DIM 128
#define CAP 64   // per-node bucket capacity; deg ~ Poisson(16), P(deg>=64) ~ 2e-18/node
#define LROW 69  // LDS row stride in u32 (276B): <=2-way bank alias on all accesses
#define NB1 512  // bin1 blocks inside merged build kernel
#define STAGE 3328  // LDS staging capacity (>= ceil(E/NB1) for E<=1.7M)

__device__ __forceinline__ float bflo(uint32_t v) {
    uint32_t b = v << 16;
    float f; __builtin_memcpy(&f, &b, 4); return f;
}
__device__ __forceinline__ float bfhi(uint32_t v) {
    uint32_t b = v & 0xffff0000u;
    float f; __builtin_memcpy(&f, &b, 4); return f;
}
__device__ __forceinline__ u16 f2bf(float f) {
    uint32_t x; __builtin_memcpy(&x, &f, 4);
    uint32_t r = (x + 0x7fffu + ((x >> 16) & 1u)) >> 16;
    return (u16)r;
}
__device__ __forceinline__ uint32_t pack2bf(float a, float b) {
    return (uint32_t)f2bf(a) | ((uint32_t)f2bf(b) << 16);
}

// ---------------- merged build: bin1 (counting-sort) + transpose + cast + zero ------

__global__ __launch_bounds__(256) void k_build(
    const int* __restrict__ src, const int* __restrict__ dst,
    uint32_t* __restrict__ gCur, uint32_t* __restrict__ groupBuf,
    int E, int ngrp, int gcap,
    const float* __restrict__ feat, uint32_t* __restrict__ X0,
    uint32_t* __restrict__ X1, uint32_t* __restrict__ X2, int N,
    const float* __restrict__ W1, const float* __restrict__ W2,
    const float* __restrict__ W3,
    u16* __restrict__ t0, u16* __restrict__ t1, u16* __restrict__ t2)
{
    __shared__ uint32_t hcnt[512];
    __shared__ uint32_t hbase[512];
    __shared__ uint32_t lbase[512];
    __shared__ uint32_t hcur[512];
    __shared__ uint32_t psum[256];
    __shared__ uint32_t sval[STAGE];
    __shared__ uint32_t starg[STAGE];

    int b = blockIdx.x;
    if (b < NB1) {
        int per = (E + NB1 - 1) / NB1;
        int lo = b * per;
        int hi = lo + per; if (hi > E) hi = E;
        int cntE = hi - lo;
        int t = threadIdx.x;

        for (int k = t; k < 512; k += 256) { hcnt[k] = 0; hcur[k] = 0; }
        __syncthreads();

        for (int i = lo + t; i < hi; i += 256)
            atomicAdd(&hcnt[((uint32_t)dst[i]) >> 8], 1u);
        __syncthreads();

        int rot = (b * 37) % (ngrp > 0 ? ngrp : 1);
        for (int k = t; k < ngrp; k += 256) {
            int g = k + rot; if (g >= ngrp) g -= ngrp;
            uint32_t c = hcnt[g];
            hbase[g] = c ? atomicAdd(&gCur[g], c) : 0u;
        }
        uint32_t ea = hcnt[2 * t], eb = hcnt[2 * t + 1];
        psum[t] = ea + eb;
        __syncthreads();
        for (int off = 1; off < 256; off <<= 1) {
            uint32_t u = (t >= off) ? psum[t - off] : 0u;
            __syncthreads();
            psum[t] += u;
            __syncthreads();
        }
        uint32_t ex = psum[t] - (ea + eb);
        lbase[2 * t] = ex;
        lbase[2 * t + 1] = ex + ea;
        __syncthreads();

        if (cntE <= STAGE) {
            for (int i = lo + t; i < hi; i += 256) {
                uint32_t d = (uint32_t)dst[i];
                uint32_t g = d >> 8;
                uint32_t pos = atomicAdd(&hcur[g], 1u);
                uint32_t li = lbase[g] + pos;
                uint32_t go = hbase[g] + pos;
                sval[li] = (uint32_t)src[i] | ((d & 255u) << 20);
                starg[li] = (go < (uint32_t)gcap)
                              ? (uint32_t)(g * (uint32_t)gcap + go) : 0xFFFFFFFFu;
            }
            __syncthreads();
            for (int i = t; i < cntE; i += 256) {
                uint32_t tg = starg[i];
                if (tg != 0xFFFFFFFFu) groupBuf[tg] = sval[i];
            }
        } else {
            for (int i = lo + t; i < hi; i += 256) {
                uint32_t d = (uint32_t)dst[i];
                uint32_t g = d >> 8;
                uint32_t off = hbase[g] + atomicAdd(&hcur[g], 1u);
                if (off < (uint32_t)gcap)
                    groupBuf[(size_t)g * gcap + off] = (uint32_t)src[i] | ((d & 255u) << 20);
            }
        }
    } else if (b < NB1 + 3) {
        int wi = b - NB1;
        const float* w = wi == 0 ? W1 : (wi == 1 ? W2 : W3);
        u16* o = wi == 0 ? t0 : (wi == 1 ? t1 : t2);
        for (int idx = threadIdx.x; idx < DIM * DIM; idx += blockDim.x) {
            int r = idx >> 7, c = idx & 127;
            o[c * DIM + r] = f2bf(w[idx]);
        }
    } else if (b == NB1 + 3) {
        int t = threadIdx.x;
        if (t < 64)       X0[(size_t)N * 64 + t] = 0u;
        else if (t < 128) X1[(size_t)N * 64 + (t - 64)] = 0u;
        else if (t < 192) X2[(size_t)N * 64 + (t - 128)] = 0u;
    } else {
        int n4 = N * 32;
        int i = (b - (NB1 + 4)) * 256 + threadIdx.x;
        int stride = (gridDim.x - (NB1 + 4)) * 256;
        const float4* in4 = (const float4*)feat;
        uint2* out2 = (uint2*)X0;
        for (; i < n4; i += stride) {
            float4 v = in4[i];
            uint2 r;
            r.x = pack2bf(v.x, v.y);
            r.y = pack2bf(v.z, v.w);
            out2[i] = r;
        }
    }
}

// ---------------- bin2: scatter group records into per-node buckets ----------------

__global__ __launch_bounds__(512) void k_bin2(
    const uint32_t* __restrict__ groupBuf, const uint32_t* __restrict__ gCur,
    uint32_t* __restrict__ bucket, uint32_t* __restrict__ cnt,
    int N, int gcap)
{
    __shared__ uint32_t ncur[256];
    int g = blockIdx.x;
    if (threadIdx.x < 256) ncur[threadIdx.x] = 0;
    __syncthreads();
    uint32_t m = gCur[g]; if (m > (uint32_t)gcap) m = gcap;
    int nodebase = g << 8;
    const uint32_t* buf = groupBuf + (size_t)g * gcap;
    for (uint32_t i = threadIdx.x; i < m; i += 512) {
        uint32_t v = buf[i];
        uint32_t nl = v >> 20;
        uint32_t s = v & 0xFFFFFu;
        uint32_t pos = atomicAdd(&ncur[nl], 1u);   // LDS atomic
        if (pos < CAP) bucket[(size_t)(nodebase + (int)nl) * CAP + pos] = s;
    }
    __syncthreads();
    int node = nodebase + threadIdx.x;
    if (threadIdx.x < 256 && node < N) cnt[node] = ncur[threadIdx.x];
}

// ---------------- fused gather + LN + GEMM, WAVE-PRIVATE (no barrier) ----------------
// Block = 256 thr (4 INDEPENDENT waves). Wave owns a 16-row tile: gathers its 16
// nodes as 8 pairs (r15/r18-proven inner structure), LN -> private LDS region,
// then (same wave, no __syncthreads) 8 col-tiles x 4 MFMAs, store.
// Straggler: sum-of-16-nodes (CV~6%) instead of block max-of-8-waves.

template <int RELU, int OUTF32>
__global__ __launch_bounds__(256) void k_fused(
    const uint32_t* __restrict__ xin, const uint32_t* __restrict__ cnt,
    const uint32_t* __restrict__ bucket,
    const int* __restrict__ src, const int* __restrict__ dst,
    const float* __restrict__ gamma, const float* __restrict__ beta,
    const u16* __restrict__ wt, const float* __restrict__ bias,
    void* __restrict__ outp, int N, int E)
{
    __shared__ uint32_t lds[4 * 16 * LROW];
    int w = threadIdx.x >> 6, l = threadIdx.x & 63;
    int tile = __builtin_amdgcn_readfirstlane(blockIdx.x * 4 + w);
    int base = tile * 16;
    uint32_t* wlds = &lds[w * 16 * LROW];   // wave-private region

    float gg0 = gamma[2 * l], gg1 = gamma[2 * l + 1];
    float bb0 = beta[2 * l],  bb1 = beta[2 * l + 1];

    // ---- gather + LN: 16 nodes as 8 pairs ----
    for (int nn = 0; nn < 16; nn += 2) {
        int node0 = base + nn;            // wave-uniform (tile is readfirstlane'd)
        int node1 = node0 + 1;
        int n0c = node0 < N ? node0 : N - 1;
        int n1c = node1 < N ? node1 : N - 1;
        uint32_t c0 = (node0 < N) ? cnt[n0c] : 0u;
        uint32_t c1 = (node1 < N) ? cnt[n1c] : 0u;
        float a0 = 0.f, a1 = 0.f, b0 = 0.f, b1 = 0.f;

        if (__builtin_expect(c0 > CAP || c1 > CAP, 0)) {
            for (int e = 0; e < E; ++e) {
                int d = dst[e];
                if (d == node0) { uint32_t v = xin[(size_t)src[e] * 64 + l]; a0 += bflo(v); a1 += bfhi(v); }
                else if (d == node1) { uint32_t v = xin[(size_t)src[e] * 64 + l]; b0 += bflo(v); b1 += bfhi(v); }
            }
        } else {
            {
                uint32_t bktv = bucket[(size_t)n0c * CAP + l];
#pragma unroll
                for (int g = 0; g < 4; ++g) {
                    if ((uint32_t)(g * 16) < c0) {
                        uint32_t v[16];
#pragma unroll
                        for (int i = 0; i < 16; ++i) {
                            const int SLOT = g * 16 + i;
                            uint32_t su = (uint32_t)__builtin_amdgcn_readfirstlane(
                                (int)((uint32_t)__builtin_amdgcn_readlane(bktv, SLOT)));
                            su = ((uint32_t)SLOT < c0) ? su : (uint32_t)N;
                            v[i] = (xin + (size_t)su * 64)[l];
                        }
#pragma unroll
                        for (int i = 0; i < 16; ++i) { a0 += bflo(v[i]); a1 += bfhi(v[i]); }
                    }
                }
            }
            {
                uint32_t bktv = bucket[(size_t)n1c * CAP + l];
#pragma unroll
                for (int g = 0; g < 4; ++g) {
                    if ((uint32_t)(g * 16) < c1) {
                        uint32_t v[16];
#pragma unroll
                        for (int i = 0; i < 16; ++i) {
                            const int SLOT = g * 16 + i;
                            uint32_t su = (uint32_t)__builtin_amdgcn_readfirstlane(
                                (int)((uint32_t)__builtin_amdgcn_readlane(bktv, SLOT)));
                            su = ((uint32_t)SLOT < c1) ? su : (uint32_t)N;
                            v[i] = (xin + (size_t)su * 64)[l];
                        }
#pragma unroll
                        for (int i = 0; i < 16; ++i) { b0 += bflo(v[i]); b1 += bfhi(v[i]); }
                    }
                }
            }
        }

        float sA = a0 + a1, qA = a0 * a0 + a1 * a1;
        float sB = b0 + b1, qB = b0 * b0 + b1 * b1;
        for (int off = 32; off; off >>= 1) {
            sA += __shfl_xor(sA, off, 64);
            sB += __shfl_xor(sB, off, 64);
            qA += __shfl_xor(qA, off, 64);
            qB += __shfl_xor(qB, off, 64);
        }
        {
            float mean = sA * (1.f / 128.f);
            float var  = qA * (1.f / 128.f) - mean * mean;
            float rs   = rsqrtf(var + 1e-5f);
            wlds[nn * LROW + l] =
                pack2bf((a0 - mean) * rs * gg0 + bb0, (a1 - mean) * rs * gg1 + bb1);
        }
        {
            float mean = sB * (1.f / 128.f);
            float var  = qB * (1.f / 128.f) - mean * mean;
            float rs   = rsqrtf(var + 1e-5f);
            wlds[(nn + 1) * LROW + l] =
                pack2bf((b0 - mean) * rs * gg0 + bb0, (b1 - mean) * rs * gg1 + bb1);
        }
    }

    // ---- GEMM phase: same wave consumes its own LDS (no barrier needed) ----
    int lr = l & 15, lg = l >> 4;
    const u16* ldsu = (const u16*)wlds;
    short8 afrag[4];
#pragma unroll
    for (int kc = 0; kc < 4; ++kc)
        afrag[kc] = *(const short8*)&ldsu[lr * (LROW * 2) + kc * 32 + lg * 8];

#pragma unroll
    for (int ct = 0; ct < 8; ++ct) {
        int col = ct * 16 + lr;
        short8 bfrag[4];
#pragma unroll
        for (int kc = 0; kc < 4; ++kc)
            bfrag[kc] = *(const short8*)(wt + (size_t)col * DIM + kc * 32 + lg * 8);

        f32x4 acc = {0.f, 0.f, 0.f, 0.f};
#pragma unroll
        for (int kc = 0; kc < 4; ++kc)
            acc = __builtin_amdgcn_mfma_f32_16x16x32_bf16(afrag[kc], bfrag[kc], acc, 0, 0, 0);

        float bv = bias[col];
#pragma unroll
        for (int j = 0; j < 4; ++j) {
            int row = base + lg * 4 + j;
            float v = acc[j] + bv;
            if (RELU) v = fmaxf(v, 0.f);
            if (row < N) {
                if (OUTF32) ((float*)outp)[(size_t)row * DIM + col] = v;
                else        ((u16*)outp)[(size_t)row * DIM + col] = f2bf(v);
            }
        }
    }
}

// ---------------- launch ----------------

extern "C" void kernel_launch(void* const* d_in, const int* in_sizes, int n_in,
                              void* d_out, int out_size, void* d_ws, size_t ws_size,
                              hipStream_t stream) {
    const float* feat = (const float*)d_in[0];
    const int* src  = (const int*)d_in[1];
    const int* dst  = (const int*)d_in[2];
    const float* g1 = (const float*)d_in[3],  *be1 = (const float*)d_in[4];
    const float* W1 = (const float*)d_in[5],  *b1  = (const float*)d_in[6];
    const float* g2 = (const float*)d_in[7],  *be2 = (const float*)d_in[8];
    const float* W2 = (const float*)d_in[9],  *b2  = (const float*)d_in[10];
    const float* g3 = (const float*)d_in[11], *be3 = (const float*)d_in[12];
    const float* W3 = (const float*)d_in[13], *b3  = (const float*)d_in[14];

    int N = in_sizes[0] / DIM;
    int E = in_sizes[1];
    float* out = (float*)d_out;

    int ngrp = (N + 255) >> 8;                 // 391 for N=100000 (max 512)
    int gcap = (E / (ngrp > 0 ? ngrp : 1)) * 3 / 2 + 1024;

    char* ws = (char*)d_ws;
    auto alloc = [&](size_t bytes) {
        char* p = ws;
        ws += (bytes + 255) & ~(size_t)255;
        return p;
    };
    uint32_t* gCur     = (uint32_t*)alloc((size_t)ngrp * 4);
    uint32_t* groupBuf = (uint32_t*)alloc((size_t)ngrp * gcap * 4);
    uint32_t* cnt      = (uint32_t*)alloc((size_t)N * 4);
    uint32_t* bucket   = (uint32_t*)alloc((size_t)N * CAP * 4);
    u16* wt1 = (u16*)alloc(DIM * DIM * 2);
    u16* wt2 = (u16*)alloc(DIM * DIM * 2);
    u16* wt3 = (u16*)alloc(DIM * DIM * 2);
    // N+1 rows: row N is the zero row targeted by invalid slots
    uint32_t* X0 = (uint32_t*)alloc((size_t)(N + 1) * 64 * 4);
    uint32_t* X1 = (uint32_t*)alloc((size_t)(N + 1) * 64 * 4);
    uint32_t* X2 = (uint32_t*)alloc((size_t)(N + 1) * 64 * 4);

    hipMemsetAsync(gCur, 0, (size_t)ngrp * 4, stream);
    k_build<<<NB1 + 4 + 1024, 256, 0, stream>>>(src, dst, gCur, groupBuf, E, ngrp, gcap,
                                                feat, X0, X1, X2, N, W1, W2, W3, wt1, wt2, wt3);
    k_bin2<<<ngrp, 512, 0, stream>>>(groupBuf, gCur, bucket, cnt, N, gcap);

    int fblocks = (N + 63) / 64;

    // ping-pong: fused kernel never reads and writes the same buffer
    k_fused<1, 0><<<fblocks, 256, 0, stream>>>(X0, cnt, bucket, src, dst, g1, be1, wt1, b1, X1,  N, E);
    k_fused<1, 0><<<fblocks, 256, 0, stream>>>(X1, cnt, bucket, src, dst, g2, be2, wt2, b2, X2,  N, E);
    k_fused<0, 1><<<fblocks, 256, 0, stream>>>(X2, cnt, bucket, src, dst, g3, be3, wt3, b3, out, N, E);
}

// Round 20
// 256.811 us; speedup vs baseline: 1.1722x; 1.1722x over previous
//
#include <hip/hip_runtime.h>
#include <hip/hip_bf16.h>
#include <stdint.h>

typedef unsigned short u16;
typedef __attribute__((ext_vector_type(8))) short short8;
typedef __attribute__((ext_vector_type(4))) float f32x4;

#define DIM 128
#define CAP 64   // per-node bucket capacity; deg ~ Poisson(16), P(deg>=64) ~ 2e-18/node
#define LROW 69  // LDS row stride in u32 (276B): bank=(5lr+4lg)%32 -> <=2-way (free)
#define NB1 512  // bin1 blocks inside merged build kernel
#define STAGE 3328  // LDS staging capacity (>= ceil(E/NB1) for E<=1.7M)

__device__ __forceinline__ float bflo(uint32_t v) {
    uint32_t b = v << 16;
    float f; __builtin_memcpy(&f, &b, 4); return f;
}
__device__ __forceinline__ float bfhi(uint32_t v) {
    uint32_t b = v & 0xffff0000u;
    float f; __builtin_memcpy(&f, &b, 4); return f;
}
__device__ __forceinline__ u16 f2bf(float f) {
    uint32_t x; __builtin_memcpy(&x, &f, 4);
    uint32_t r = (x + 0x7fffu + ((x >> 16) & 1u)) >> 16;
    return (u16)r;
}
__device__ __forceinline__ uint32_t pack2bf(float a, float b) {
    return (uint32_t)f2bf(a) | ((uint32_t)f2bf(b) << 16);
}

// ---------------- merged build: bin1 (counting-sort) + transpose + cast + zero ------
// blocks [0,NB1): bin1 with LDS staging -> group-major ordered copy-out
// (piecewise-contiguous global writes instead of random 4B scatter);
// [NB1,NB1+3): W transpose; NB1+3: zero rows; rest: feature cast.

__global__ __launch_bounds__(256) void k_build(
    const int* __restrict__ src, const int* __restrict__ dst,
    uint32_t* __restrict__ gCur, uint32_t* __restrict__ groupBuf,
    int E, int ngrp, int gcap,
    const float* __restrict__ feat, uint32_t* __restrict__ X0,
    uint32_t* __restrict__ X1, uint32_t* __restrict__ X2, int N,
    const float* __restrict__ W1, const float* __restrict__ W2,
    const float* __restrict__ W3,
    u16* __restrict__ t0, u16* __restrict__ t1, u16* __restrict__ t2)
{
    __shared__ uint32_t hcnt[512];
    __shared__ uint32_t hbase[512];
    __shared__ uint32_t lbase[512];
    __shared__ uint32_t hcur[512];
    __shared__ uint32_t psum[256];
    __shared__ uint32_t sval[STAGE];
    __shared__ uint32_t starg[STAGE];

    int b = blockIdx.x;
    if (b < NB1) {
        int per = (E + NB1 - 1) / NB1;
        int lo = b * per;
        int hi = lo + per; if (hi > E) hi = E;
        int cntE = hi - lo;
        int t = threadIdx.x;

        for (int k = t; k < 512; k += 256) { hcnt[k] = 0; hcur[k] = 0; }
        __syncthreads();

        // phase A: LDS histogram of coarse groups
        for (int i = lo + t; i < hi; i += 256)
            atomicAdd(&hcnt[((uint32_t)dst[i]) >> 8], 1u);
        __syncthreads();

        // phase B1: reserve global space per (block, group); rotate to de-contend
        int rot = (b * 37) % (ngrp > 0 ? ngrp : 1);
        for (int k = t; k < ngrp; k += 256) {
            int g = k + rot; if (g >= ngrp) g -= ngrp;
            uint32_t c = hcnt[g];
            hbase[g] = c ? atomicAdd(&gCur[g], c) : 0u;
        }
        // phase B2: local exclusive scan of hcnt (512 entries, pairwise + 256-scan)
        uint32_t ea = hcnt[2 * t], eb = hcnt[2 * t + 1];
        psum[t] = ea + eb;
        __syncthreads();
        for (int off = 1; off < 256; off <<= 1) {
            uint32_t u = (t >= off) ? psum[t - off] : 0u;
            __syncthreads();
            psum[t] += u;
            __syncthreads();
        }
        uint32_t ex = psum[t] - (ea + eb);
        lbase[2 * t] = ex;
        lbase[2 * t + 1] = ex + ea;
        __syncthreads();

        if (cntE <= STAGE) {
            // phase C: scatter into LDS staging, group-major; record final target
            for (int i = lo + t; i < hi; i += 256) {
                uint32_t d = (uint32_t)dst[i];
                uint32_t g = d >> 8;
                uint32_t pos = atomicAdd(&hcur[g], 1u);
                uint32_t li = lbase[g] + pos;
                uint32_t go = hbase[g] + pos;
                sval[li] = (uint32_t)src[i] | ((d & 255u) << 20);
                starg[li] = (go < (uint32_t)gcap)
                              ? (uint32_t)(g * (uint32_t)gcap + go) : 0xFFFFFFFFu;
            }
            __syncthreads();
            // phase D: ordered copy-out — piecewise-contiguous global writes
            for (int i = t; i < cntE; i += 256) {
                uint32_t tg = starg[i];
                if (tg != 0xFFFFFFFFu) groupBuf[tg] = sval[i];
            }
        } else {
            // fallback: direct scatter (generic E)
            for (int i = lo + t; i < hi; i += 256) {
                uint32_t d = (uint32_t)dst[i];
                uint32_t g = d >> 8;
                uint32_t off = hbase[g] + atomicAdd(&hcur[g], 1u);
                if (off < (uint32_t)gcap)
                    groupBuf[(size_t)g * gcap + off] = (uint32_t)src[i] | ((d & 255u) << 20);
            }
        }
    } else if (b < NB1 + 3) {
        int wi = b - NB1;
        const float* w = wi == 0 ? W1 : (wi == 1 ? W2 : W3);
        u16* o = wi == 0 ? t0 : (wi == 1 ? t1 : t2);
        for (int idx = threadIdx.x; idx < DIM * DIM; idx += blockDim.x) {
            int r = idx >> 7, c = idx & 127;
            o[c * DIM + r] = f2bf(w[idx]);
        }
    } else if (b == NB1 + 3) {
        int t = threadIdx.x;
        if (t < 64)       X0[(size_t)N * 64 + t] = 0u;
        else if (t < 128) X1[(size_t)N * 64 + (t - 64)] = 0u;
        else if (t < 192) X2[(size_t)N * 64 + (t - 128)] = 0u;
    } else {
        int n4 = N * 32;
        int i = (b - (NB1 + 4)) * 256 + threadIdx.x;
        int stride = (gridDim.x - (NB1 + 4)) * 256;
        const float4* in4 = (const float4*)feat;
        uint2* out2 = (uint2*)X0;
        for (; i < n4; i += stride) {
            float4 v = in4[i];
            uint2 r;
            r.x = pack2bf(v.x, v.y);
            r.y = pack2bf(v.z, v.w);
            out2[i] = r;
        }
    }
}

// ---------------- bin2: scatter group records into per-node buckets ----------------

__global__ __launch_bounds__(512) void k_bin2(
    const uint32_t* __restrict__ groupBuf, const uint32_t* __restrict__ gCur,
    uint32_t* __restrict__ bucket, uint32_t* __restrict__ cnt,
    int N, int gcap)
{
    __shared__ uint32_t ncur[256];
    int g = blockIdx.x;
    if (threadIdx.x < 256) ncur[threadIdx.x] = 0;
    __syncthreads();
    uint32_t m = gCur[g]; if (m > (uint32_t)gcap) m = gcap;
    int nodebase = g << 8;
    const uint32_t* buf = groupBuf + (size_t)g * gcap;
    for (uint32_t i = threadIdx.x; i < m; i += 512) {
        uint32_t v = buf[i];
        uint32_t nl = v >> 20;
        uint32_t s = v & 0xFFFFFu;
        uint32_t pos = atomicAdd(&ncur[nl], 1u);   // LDS atomic
        if (pos < CAP) bucket[(size_t)(nodebase + (int)nl) * CAP + pos] = s;
    }
    __syncthreads();
    int node = nodebase + threadIdx.x;
    if (threadIdx.x < 256 && node < N) cnt[node] = ncur[threadIdx.x];
}

// ---------------- fused gather + LN + GEMM (r18-proven best) ----------------

template <int RELU, int OUTF32>
__global__ __launch_bounds__(512) void k_fused(
    const uint32_t* __restrict__ xin, const uint32_t* __restrict__ cnt,
    const uint32_t* __restrict__ bucket,
    const int* __restrict__ src, const int* __restrict__ dst,
    const float* __restrict__ gamma, const float* __restrict__ beta,
    const u16* __restrict__ wt, const float* __restrict__ bias,
    void* __restrict__ outp, int N, int E)
{
    __shared__ uint32_t lds[16 * LROW];
    int w = threadIdx.x >> 6, l = threadIdx.x & 63;
    int base = blockIdx.x * 16;
    int lr = l & 15, lg = l >> 4;

    // hoisted GEMM operands (independent of gather; issue early)
    int col = w * 16 + lr;
    short8 bfrag[4];
#pragma unroll
    for (int kc = 0; kc < 4; ++kc)
        bfrag[kc] = *(const short8*)(wt + (size_t)col * DIM + kc * 32 + lg * 8);
    float bv = bias[col];

    // gather phase (scalar-addressed, 16-deep, 2 nodes/wave)
    int node0 = __builtin_amdgcn_readfirstlane(base + 2 * w);
    int node1 = node0 + 1;
    int n0c = node0 < N ? node0 : N - 1;
    int n1c = node1 < N ? node1 : N - 1;
    uint32_t c0 = (node0 < N) ? cnt[n0c] : 0u;
    uint32_t c1 = (node1 < N) ? cnt[n1c] : 0u;
    float a0 = 0.f, a1 = 0.f, b0 = 0.f, b1 = 0.f;

    if (__builtin_expect(c0 > CAP || c1 > CAP, 0)) {
        for (int e = 0; e < E; ++e) {
            int d = dst[e];
            if (d == node0) { uint32_t v = xin[(size_t)src[e] * 64 + l]; a0 += bflo(v); a1 += bfhi(v); }
            else if (d == node1) { uint32_t v = xin[(size_t)src[e] * 64 + l]; b0 += bflo(v); b1 += bfhi(v); }
        }
    } else {
        {
            uint32_t bktv = bucket[(size_t)n0c * CAP + l];
#pragma unroll
            for (int g = 0; g < 4; ++g) {
                if ((uint32_t)(g * 16) < c0) {
                    uint32_t v[16];
#pragma unroll
                    for (int i = 0; i < 16; ++i) {
                        const int SLOT = g * 16 + i;
                        uint32_t su = (uint32_t)__builtin_amdgcn_readfirstlane(
                            (int)((uint32_t)__builtin_amdgcn_readlane(bktv, SLOT)));
                        su = ((uint32_t)SLOT < c0) ? su : (uint32_t)N;
                        v[i] = (xin + (size_t)su * 64)[l];
                    }
#pragma unroll
                    for (int i = 0; i < 16; ++i) { a0 += bflo(v[i]); a1 += bfhi(v[i]); }
                }
            }
        }
        {
            uint32_t bktv = bucket[(size_t)n1c * CAP + l];
#pragma unroll
            for (int g = 0; g < 4; ++g) {
                if ((uint32_t)(g * 16) < c1) {
                    uint32_t v[16];
#pragma unroll
                    for (int i = 0; i < 16; ++i) {
                        const int SLOT = g * 16 + i;
                        uint32_t su = (uint32_t)__builtin_amdgcn_readfirstlane(
                            (int)((uint32_t)__builtin_amdgcn_readlane(bktv, SLOT)));
                        su = ((uint32_t)SLOT < c1) ? su : (uint32_t)N;
                        v[i] = (xin + (size_t)su * 64)[l];
                    }
#pragma unroll
                    for (int i = 0; i < 16; ++i) { b0 += bflo(v[i]); b1 += bfhi(v[i]); }
                }
            }
        }
    }

    float sA = a0 + a1, qA = a0 * a0 + a1 * a1;
    float sB = b0 + b1, qB = b0 * b0 + b1 * b1;
    for (int off = 32; off; off >>= 1) {
        sA += __shfl_xor(sA, off, 64);
        sB += __shfl_xor(sB, off, 64);
        qA += __shfl_xor(qA, off, 64);
        qB += __shfl_xor(qB, off, 64);
    }
    float gg0 = gamma[2 * l], gg1 = gamma[2 * l + 1];
    float bb0 = beta[2 * l],  bb1 = beta[2 * l + 1];
    {
        float mean = sA * (1.f / 128.f);
        float var  = qA * (1.f / 128.f) - mean * mean;
        float rs   = rsqrtf(var + 1e-5f);
        lds[(2 * w) * LROW + l] =
            pack2bf((a0 - mean) * rs * gg0 + bb0, (a1 - mean) * rs * gg1 + bb1);
    }
    {
        float mean = sB * (1.f / 128.f);
        float var  = qB * (1.f / 128.f) - mean * mean;
        float rs   = rsqrtf(var + 1e-5f);
        lds[(2 * w + 1) * LROW + l] =
            pack2bf((b0 - mean) * rs * gg0 + bb0, (b1 - mean) * rs * gg1 + bb1);
    }
    __syncthreads();

    // GEMM phase: pure LDS + MFMA + store
    const u16* ldsu = (const u16*)lds;
    short8 afrag[4];
#pragma unroll
    for (int kc = 0; kc < 4; ++kc)
        afrag[kc] = *(const short8*)&ldsu[lr * (LROW * 2) + kc * 32 + lg * 8];

    f32x4 acc = {0.f, 0.f, 0.f, 0.f};
#pragma unroll
    for (int kc = 0; kc < 4; ++kc)
        acc = __builtin_amdgcn_mfma_f32_16x16x32_bf16(afrag[kc], bfrag[kc], acc, 0, 0, 0);

#pragma unroll
    for (int j = 0; j < 4; ++j) {
        int row = base + lg * 4 + j;
        float v = acc[j] + bv;
        if (RELU) v = fmaxf(v, 0.f);
        if (row < N) {
            if (OUTF32) ((float*)outp)[(size_t)row * DIM + col] = v;
            else        ((u16*)outp)[(size_t)row * DIM + col] = f2bf(v);
        }
    }
}

// ---------------- launch ----------------

extern "C" void kernel_launch(void* const* d_in, const int* in_sizes, int n_in,
                              void* d_out, int out_size, void* d_ws, size_t ws_size,
                              hipStream_t stream) {
    const float* feat = (const float*)d_in[0];
    const int* src  = (const int*)d_in[1];
    const int* dst  = (const int*)d_in[2];
    const float* g1 = (const float*)d_in[3],  *be1 = (const float*)d_in[4];
    const float* W1 = (const float*)d_in[5],  *b1  = (const float*)d_in[6];
    const float* g2 = (const float*)d_in[7],  *be2 = (const float*)d_in[8];
    const float* W2 = (const float*)d_in[9],  *b2  = (const float*)d_in[10];
    const float* g3 = (const float*)d_in[11], *be3 = (const float*)d_in[12];
    const float* W3 = (const float*)d_in[13], *b3  = (const float*)d_in[14];

    int N = in_sizes[0] / DIM;
    int E = in_sizes[1];
    float* out = (float*)d_out;

    int ngrp = (N + 255) >> 8;                 // 391 for N=100000 (max 512)
    int gcap = (E / (ngrp > 0 ? ngrp : 1)) * 3 / 2 + 1024;

    char* ws = (char*)d_ws;
    auto alloc = [&](size_t bytes) {
        char* p = ws;
        ws += (bytes + 255) & ~(size_t)255;
        return p;
    };
    uint32_t* gCur     = (uint32_t*)alloc((size_t)ngrp * 4);
    uint32_t* groupBuf = (uint32_t*)alloc((size_t)ngrp * gcap * 4);
    uint32_t* cnt      = (uint32_t*)alloc((size_t)N * 4);
    uint32_t* bucket   = (uint32_t*)alloc((size_t)N * CAP * 4);
    u16* wt1 = (u16*)alloc(DIM * DIM * 2);
    u16* wt2 = (u16*)alloc(DIM * DIM * 2);
    u16* wt3 = (u16*)alloc(DIM * DIM * 2);
    // N+1 rows: row N is the zero row targeted by invalid slots
    uint32_t* X0 = (uint32_t*)alloc((size_t)(N + 1) * 64 * 4);
    uint32_t* X1 = (uint32_t*)alloc((size_t)(N + 1) * 64 * 4);
    uint32_t* X2 = (uint32_t*)alloc((size_t)(N + 1) * 64 * 4);

    hipMemsetAsync(gCur, 0, (size_t)ngrp * 4, stream);
    k_build<<<NB1 + 4 + 1024, 256, 0, stream>>>(src, dst, gCur, groupBuf, E, ngrp, gcap,
                                                feat, X0, X1, X2, N, W1, W2, W3, wt1, wt2, wt3);
    k_bin2<<<ngrp, 512, 0, stream>>>(groupBuf, gCur, bucket, cnt, N, gcap);

    int fblocks = (N + 15) / 16;

    // ping-pong: fused kernel never reads and writes the same buffer
    k_fused<1, 0><<<fblocks, 512, 0, stream>>>(X0, cnt, bucket, src, dst, g1, be1, wt1, b1, X1,  N, E);
    k_fused<1, 0><<<fblocks, 512, 0, stream>>>(X1, cnt, bucket, src, dst, g2, be2, wt2, b2, X2,  N, E);
    k_fused<0, 1><<<fblocks, 512, 0, stream>>>(X2, cnt, bucket, src, dst, g3, be3, wt3, b3, out, N, E);
}